// Round 9
// baseline (812.071 us; speedup 1.0000x reference)
//
#include <hip/hip_runtime.h>
#include <hip/hip_bf16.h>

#define NN 100000
#define DD 128
#define MM 3
#define EE 1600000
#define CH_NODES 512                          // nodes per coarse chunk
#define NC ((NN + CH_NODES - 1) / CH_NODES)   // 196 coarse chunks
#define ECAP 10752                            // per-chunk PADDED capacity (8192 mean + 8.5σ + 3/node pad)
#define ECHTOT ((size_t)NC * ECAP)            // per-m CSR capacity
#define TILE_E 8192
#define NTILES ((EE + TILE_E - 1) / TILE_E)   // 196
#define DTILE 2048
#define NT2 ((NN + DTILE - 1) / DTILE)        // 49 node tiles for degsort
#define NT2P 52                               // padded pitch
#define DBINS 512
#define HSCALE 64.0f
#define HINV (1.0f / 64.0f)
#define PADMARK 0xFFFFFFFFu

typedef unsigned int uint32_hip;
typedef short short8 __attribute__((ext_vector_type(8)));
typedef float floatx4 __attribute__((ext_vector_type(4)));
typedef float floatx2 __attribute__((ext_vector_type(2)));

// ---- bf16 helpers ----
__device__ __forceinline__ float bf2f(short s) {
  return __uint_as_float(((uint32_hip)(unsigned short)s) << 16);
}
__device__ __forceinline__ unsigned short f2bf(float f) {
  union { __hip_bfloat16 b; unsigned short u; } cv;
  cv.b = __float2bfloat16(f);
  return cv.u;
}
__device__ __forceinline__ uint32_hip packbf2(float x, float y) {
  return (uint32_hip)f2bf(x) | ((uint32_hip)f2bf(y) << 16);
}
__device__ __forceinline__ float tanh_apx(float x) {
  float e = __expf(2.0f * x);
  return 1.0f - 2.0f / (e + 1.0f);
}
// pack 4 floats -> 4 fp8 e4m3 (OCP on gfx950) in one uint
__device__ __forceinline__ uint32_hip pack_fp8x4(float a, float b, float c, float d) {
  uint32_hip w = 0;
  w = __builtin_amdgcn_cvt_pk_fp8_f32(a, b, w, false);  // bytes 0,1
  w = __builtin_amdgcn_cvt_pk_fp8_f32(c, d, w, true);   // bytes 2,3
  return w;
}
// fp16 (in low 16 bits) -> f32
__device__ __forceinline__ float h2f(uint32_hip u) {
  union { unsigned short us; _Float16 h; } cv;
  cv.us = (unsigned short)u;
  return (float)cv.h;
}
__device__ __forceinline__ unsigned short f2h(float f) {
  union { unsigned short us; _Float16 h; } cv;
  cv.h = (_Float16)f;
  return cv.us;
}
// decode 16 fp8 (uint4) -> 8 float2
__device__ __forceinline__ void dec16(uint4 hv, floatx2* f) {
  f[0] = __builtin_amdgcn_cvt_pk_f32_fp8((int)hv.x, false);
  f[1] = __builtin_amdgcn_cvt_pk_f32_fp8((int)hv.x, true);
  f[2] = __builtin_amdgcn_cvt_pk_f32_fp8((int)hv.y, false);
  f[3] = __builtin_amdgcn_cvt_pk_f32_fp8((int)hv.y, true);
  f[4] = __builtin_amdgcn_cvt_pk_f32_fp8((int)hv.z, false);
  f[5] = __builtin_amdgcn_cvt_pk_f32_fp8((int)hv.z, true);
  f[6] = __builtin_amdgcn_cvt_pk_f32_fp8((int)hv.w, false);
  f[7] = __builtin_amdgcn_cvt_pk_f32_fp8((int)hv.w, true);
}

// ---------- prep: transpose+convert weights to bf16 [mat][n][k] ----------
// mats 0..5 = W[l][m]; mats 6..7 = att_w1[l]. Source is [k][n] f32.
__global__ __launch_bounds__(256) void wprep_kernel(const float* __restrict__ W,
                                                    const float* __restrict__ aw1,
                                                    unsigned short* __restrict__ wbf) {
  int tot = blockIdx.x * 256 + threadIdx.x;  // 8 * 16384
  int mat = tot >> 14;
  int i = tot & 16383;
  int n = i >> 7, k = i & 127;
  float v = (mat < 6) ? W[(size_t)mat * 16384 + k * 128 + n]
                      : aw1[(size_t)(mat - 6) * 16384 + k * 128 + n];
  wbf[tot] = f2bf(v);
}

// ---------- L1 pass A: per-tile coarse-chunk histogram -> thist[m][chunk][tile] ----------
__global__ __launch_bounds__(256) void hist1_kernel(const int* __restrict__ e0,
                                                    const int* __restrict__ e1,
                                                    const int* __restrict__ e2,
                                                    int* __restrict__ thist) {
  __shared__ int hist[NC];
  int m = blockIdx.y, tile = blockIdx.x, t = threadIdx.x;
  const int* ei = (m == 0) ? e0 : (m == 1) ? e1 : e2;
  const int* dst = ei + EE;
  int beg = tile * TILE_E, end = min(beg + TILE_E, EE);
  if (t < NC) hist[t] = 0;
  __syncthreads();
  for (int e = beg + t; e < end; e += 256) atomicAdd(&hist[dst[e] >> 9], 1);
  __syncthreads();
  int* th = thist + (size_t)m * NC * NTILES + tile;
  if (t < NC) th[(size_t)t * NTILES] = hist[t];
}

// ---------- L1 pass B: exclusive scan across tiles per (chunk,m) -> deterministic bases ----
__global__ __launch_bounds__(256) void scan1_kernel(int* __restrict__ thist,
                                                    int* __restrict__ ccount) {
  __shared__ int sw[256];
  int c = blockIdx.x, m = blockIdx.y, t = threadIdx.x;
  int* th = thist + ((size_t)m * NC + c) * NTILES;
  int v = (t < NTILES) ? th[t] : 0;
  sw[t] = v;
  __syncthreads();
  for (int off = 1; off < 256; off <<= 1) {
    int u = (t >= off) ? sw[t - off] : 0;
    __syncthreads();
    sw[t] += u;
    __syncthreads();
  }
  if (t < NTILES) th[t] = c * ECAP + sw[t] - v;  // exclusive base
  if (t == NTILES - 1) ccount[m * NC + c] = sw[t];
}

// ---------- L1 pass C: coarse scatter, LDS-sorted emit (runs of ~42 edges) ----------
__global__ __launch_bounds__(256) void scatter1_kernel(const int* __restrict__ e0,
                                                       const int* __restrict__ e1,
                                                       const int* __restrict__ e2,
                                                       const int* __restrict__ thist,
                                                       const int* __restrict__ ccount,
                                                       uint32_hip* __restrict__ lvl1) {
  __shared__ int gbase[NC];
  __shared__ int spos[NC];
  __shared__ int cur[NC];
  __shared__ int sw[256];
  __shared__ uint32_hip sval[TILE_E];
  __shared__ unsigned char sbuk[TILE_E];
  int m = blockIdx.y, tile = blockIdx.x, t = threadIdx.x;
  const int* ei = (m == 0) ? e0 : (m == 1) ? e1 : e2;
  const int* dst = ei + EE;
  const int* th = thist + (size_t)m * NC * NTILES + tile;
  int cnt = 0;
  if (t < NC) {
    int gb = th[(size_t)t * NTILES];
    int gn = (tile + 1 < NTILES) ? th[(size_t)t * NTILES + 1] : t * ECAP + ccount[m * NC + t];
    gbase[t] = gb;
    cnt = gn - gb;
  }
  sw[t] = cnt;
  __syncthreads();
  for (int off = 1; off < 256; off <<= 1) {
    int u = (t >= off) ? sw[t - off] : 0;
    __syncthreads();
    sw[t] += u;
    __syncthreads();
  }
  if (t < NC) {
    spos[t] = sw[t] - cnt;
    cur[t] = sw[t] - cnt;
  }
  __syncthreads();
  int beg = tile * TILE_E, end = min(beg + TILE_E, EE);
  int ct = end - beg;
  for (int e = beg + t; e < end; e += 256) {
    int s = ei[e], d = dst[e];
    int b = d >> 9;
    int r = atomicAdd(&cur[b], 1);
    sval[r] = (uint32_hip)s | ((uint32_hip)(d & 511) << 17);
    sbuk[r] = (unsigned char)b;
  }
  __syncthreads();
  uint32_hip* eb = lvl1 + (size_t)m * ECHTOT;
  for (int i = t; i < ct; i += 256) {
    int b = sbuk[i];
    eb[gbase[b] + (i - spos[b])] = sval[i];
  }
}

// ---------- L2: per-chunk 512-way counting sort in LDS, PADDED to 4/node ----------
__global__ __launch_bounds__(256) void sort2_kernel(uint32_hip* __restrict__ lvl1,
                                                    const int* __restrict__ ccount,
                                                    int* __restrict__ astart,
                                                    unsigned short* __restrict__ sdeg,
                                                    int* __restrict__ cpad) {
  __shared__ uint32_hip ebl[ECAP];
  __shared__ int cnt[CH_NODES];
  __shared__ int pos[CH_NODES];
  __shared__ int sw[256];
  int m = blockIdx.y, c = blockIdx.x, t = threadIdx.x;
  int base = c * ECAP;
  int ct = ccount[m * NC + c];
  uint32_hip* eb = lvl1 + (size_t)m * ECHTOT + base;
  for (int e = t; e < ct; e += 256) ebl[e] = eb[e];
  cnt[t] = 0;
  cnt[t + 256] = 0;
  __syncthreads();
  for (int e = t; e < ct; e += 256) atomicAdd(&cnt[ebl[e] >> 17], 1);
  __syncthreads();
  int c0 = cnt[2 * t], c1 = cnt[2 * t + 1];
  int p0 = (c0 + 3) & ~3, p1 = (c1 + 3) & ~3;  // padded run lengths
  int s = p0 + p1;
  sw[t] = s;
  __syncthreads();
  for (int off = 1; off < 256; off <<= 1) {
    int u = (t >= off) ? sw[t - off] : 0;
    __syncthreads();
    sw[t] += u;
    __syncthreads();
  }
  int excl = sw[t] - s;
  pos[2 * t] = excl;
  pos[2 * t + 1] = excl + p0;
  int node0 = c * CH_NODES;
  {
    int n0 = node0 + 2 * t;
    if (n0 < NN) {
      astart[(size_t)m * NN + n0] = base + excl;
      sdeg[(size_t)m * NN + n0] = (unsigned short)c0;
    }
    int n1 = node0 + 2 * t + 1;
    if (n1 < NN) {
      astart[(size_t)m * NN + n1] = base + excl + p0;
      sdeg[(size_t)m * NN + n1] = (unsigned short)c1;
    }
  }
  if (t == 255) cpad[m * NC + c] = sw[255];
  __syncthreads();
  for (int e = t; e < ct; e += 256) {
    uint32_hip p = ebl[e];
    int q = atomicAdd(&pos[p >> 17], 1);
    eb[q] = p & 0x1FFFFu;  // src only, node-sorted
  }
  // fill pad slots
  for (int i = c0; i < p0; ++i) eb[excl + i] = PADMARK;
  for (int i = c1; i < p1; ++i) eb[excl + p0 + i] = PADMARK;
}

// ---------- embed fp16 source-norm into upper 15 bits; pads become entry 0 ----------
__global__ void norm_embed_kernel(uint32_hip* __restrict__ lvl1, const int* __restrict__ cpad,
                                  const unsigned short* __restrict__ sdeg) {
  int m = blockIdx.y, c = blockIdx.x, t = threadIdx.x;
  int base = c * ECAP;
  int ct = cpad[m * NC + c];
  uint32_hip* eb = lvl1 + (size_t)m * ECHTOT + base;
  const unsigned short* sd = sdeg + (size_t)m * NN;
  for (int e = t; e < ct; e += 256) {
    uint32_hip p = eb[e];
    uint32_hip s = p & 0x1FFFFu;
    uint32_hip sc_ = (s < NN) ? s : 0;
    float dv = rsqrtf((float)(sd[sc_] + 1));
    eb[e] = (p == PADMARK) ? 0u : (s | ((uint32_hip)f2h(dv) << 17));
  }
}

// ---------- parallel degree sort: 4-stage tile radix -> pinfo[slot] ----------
__global__ __launch_bounds__(256) void dhist_kernel(const unsigned short* __restrict__ sdeg,
                                                    int* __restrict__ dthist) {
  __shared__ int hist[DBINS];
  int m = blockIdx.y, tile = blockIdx.x, t = threadIdx.x;
  const unsigned short* sd = sdeg + (size_t)m * NN;
  hist[t] = 0;
  hist[t + 256] = 0;
  __syncthreads();
  int beg = tile * DTILE, end = min(beg + DTILE, NN);
  for (int n = beg + t; n < end; n += 256) atomicAdd(&hist[min((int)sd[n], DBINS - 1)], 1);
  __syncthreads();
  int* th = dthist + ((size_t)m * DBINS) * NT2P + tile;
  th[(size_t)t * NT2P] = hist[t];
  th[(size_t)(t + 256) * NT2P] = hist[t + 256];
}

__global__ __launch_bounds__(64) void dscan_kernel(int* __restrict__ dthist,
                                                   int* __restrict__ bintot) {
  __shared__ int sw[64];
  int bin = blockIdx.x, m = blockIdx.y, t = threadIdx.x;
  int* th = dthist + ((size_t)m * DBINS + bin) * NT2P;
  int v = (t < NT2) ? th[t] : 0;
  sw[t] = v;
  __syncthreads();
  for (int off = 1; off < 64; off <<= 1) {
    int u = (t >= off) ? sw[t - off] : 0;
    __syncthreads();
    sw[t] += u;
    __syncthreads();
  }
  if (t < NT2) th[t] = sw[t] - v;  // exclusive within bin
  if (t == 63) bintot[m * DBINS + bin] = sw[63];
}

__global__ __launch_bounds__(512) void dscan2_kernel(const int* __restrict__ bintot,
                                                     int* __restrict__ binbase) {
  __shared__ int sw[DBINS];
  int m = blockIdx.x, t = threadIdx.x;
  int v = bintot[m * DBINS + t];
  sw[t] = v;
  __syncthreads();
  for (int off = 1; off < DBINS; off <<= 1) {
    int u = (t >= off) ? sw[t - off] : 0;
    __syncthreads();
    sw[t] += u;
    __syncthreads();
  }
  binbase[m * DBINS + t] = sw[t] - v;
}

__global__ __launch_bounds__(256) void dscatter_kernel(const unsigned short* __restrict__ sdeg,
                                                       const int* __restrict__ astart,
                                                       const int* __restrict__ dthist,
                                                       const int* __restrict__ binbase,
                                                       uint2* __restrict__ pinfo) {
  __shared__ int cur[DBINS];
  int m = blockIdx.y, tile = blockIdx.x, t = threadIdx.x;
  const unsigned short* sd = sdeg + (size_t)m * NN;
  const int* as_ = astart + (size_t)m * NN;
  for (int b = t; b < DBINS; b += 256)
    cur[b] = binbase[m * DBINS + b] + dthist[((size_t)m * DBINS + b) * NT2P + tile];
  __syncthreads();
  uint2* pi = pinfo + (size_t)m * NN;
  int beg = tile * DTILE, end = min(beg + DTILE, NN);
  for (int n = beg + t; n < end; n += 256) {
    int d = sd[n];
    int r = atomicAdd(&cur[min(d, DBINS - 1)], 1);
    int slot = NN - 1 - r;  // descending degree -> heavy blocks launch first
    uint2 v;
    v.x = (uint32_hip)as_[n];
    v.y = (uint32_hip)n | ((uint32_hip)d << 17);
    pi[slot] = v;
  }
}

// ---------- embedding gather -> fp8 h (x64 scale), lives in d_out ----------
__global__ void embed_kernel(const int* __restrict__ x, const float* __restrict__ tbl,
                             uint32_hip* __restrict__ hq) {
  int i = blockIdx.x * 256 + threadIdx.x;
  if (i < NN * 32) {
    int n = i >> 5;
    int c = i & 31;
    float4 v = ((const float4*)tbl)[(size_t)x[n] * 32 + c];
    hq[(size_t)n * 32 + c] =
        pack_fp8x4(v.x * HSCALE, v.y * HSCALE, v.z * HSCALE, v.w * HSCALE);
  }
}

// ---------- normalized aggregation (fp8 h -> bf16 z), STANDALONE (round-6 form) ----------
// 8 nodes/wave (degree-sorted, descending), 8 lanes/node, dwordx4 gathers,
// 4 edges/iter; CSR quad for iter i+1 prefetched during iter i.
__global__ __launch_bounds__(256) void agg_kernel(const uint32_hip* __restrict__ hq,
                                                  const uint2* __restrict__ pinfo,
                                                  const uint32_hip* __restrict__ csr,
                                                  uint32_hip* __restrict__ zall) {
  int m = blockIdx.y;
  const uint2* pi_ = pinfo + (size_t)m * NN;
  const uint32_hip* cs = csr + (size_t)m * ECHTOT;
  uint32_hip* zo = zall + (size_t)m * NN * 64;
  int t = threadIdx.x;
  int wave = t >> 6, lane = t & 63;
  int g = lane >> 3, l = lane & 7;              // group (node) / lane within group
  int slot = blockIdx.x * 32 + wave * 8 + g;    // 100000 = 32 * 3125 -> exact grid
  uint2 pi = pi_[slot];
  int e = (int)pi.x;
  int n = (int)(pi.y & 0x1FFFFu);
  int deg = (int)(pi.y >> 17);
  float di = rsqrtf((float)(deg + 1));
  floatx2 ac[8];
  {
    uint4 hv = *(const uint4*)(hq + (size_t)n * 32 + l * 4);
    floatx2 f[8];
    dec16(hv, f);
    floatx2 di2 = {di, di};
#pragma unroll
    for (int j = 0; j < 8; ++j) ac[j] = di2 * f[j];
  }
  int end = e + ((deg + 3) & ~3);
  uint4 ce = *(const uint4*)(cs + e);  // first quad (bounded; pad covers overrun)
  while (__any(e < end)) {
    int en = e + 4;
    uint4 cn = *(const uint4*)(cs + en);  // prefetch next quad
    uint32_hip msk = (e < end) ? 0xFFFFFFFFu : 0u;
    uint32_hip cearr[4] = {ce.x & msk, ce.y & msk, ce.z & msk, ce.w & msk};
#pragma unroll
    for (int k = 0; k < 4; ++k) {
      uint32_hip ck = cearr[k];
      float nk = h2f(ck >> 17);
      int sk = ck & 0x1FFFF;
      uint4 hk = *(const uint4*)(hq + (size_t)sk * 32 + l * 4);
      floatx2 fk[8];
      dec16(hk, fk);
      floatx2 n2 = {nk, nk};
#pragma unroll
      for (int j = 0; j < 8; ++j) ac[j] = __builtin_elementwise_fma(n2, fk[j], ac[j]);
    }
    ce = cn;
    e = en;
  }
  float scv = di * HINV;
  floatx2 sc2 = {scv, scv};
#pragma unroll
  for (int j = 0; j < 8; ++j) ac[j] = ac[j] * sc2;
  uint4 w0, w1;
  w0.x = packbf2(ac[0].x, ac[0].y);
  w0.y = packbf2(ac[1].x, ac[1].y);
  w0.z = packbf2(ac[2].x, ac[2].y);
  w0.w = packbf2(ac[3].x, ac[3].y);
  w1.x = packbf2(ac[4].x, ac[4].y);
  w1.y = packbf2(ac[5].x, ac[5].y);
  w1.z = packbf2(ac[6].x, ac[6].y);
  w1.w = packbf2(ac[7].x, ac[7].y);
  uint32_hip* zr = zo + (size_t)n * 64 + l * 8;
  *(uint4*)zr = w0;
  *(uint4*)(zr + 4) = w1;
}

// ---------- FUSED GEMM + semantic attention + combine (+ final log_softmax) ----------
// Per wave (16 nodes): for each m, MFMA z_m@W_m+b (B from prepped bf16 weights,
// L2-hot), bounce the 16x128 C-tile through a per-wave LDS slab to re-read in
// A-fragment layout (the C->A transpose previously done via HBM round-trip).
// Then scores via MFMA on the in-register z', softmax over m, combine.
__global__ __launch_bounds__(256) void gemm_att_kernel(
    const unsigned short* __restrict__ Z, const unsigned short* __restrict__ wbf,
    const float* __restrict__ Ball, const unsigned short* __restrict__ wb1,
    const float* __restrict__ b1, const float* __restrict__ w2,
    uint32_hip* __restrict__ hq, float* __restrict__ fout, int last) {
  __shared__ unsigned short zt[4][16][136];
  __shared__ float sc[4][3][16];
  int t = threadIdx.x;
  int wave = t >> 6, lane = t & 63;
  int quad = lane >> 4, ln = lane & 15;
  int nodebase = blockIdx.x * 64 + wave * 16;
  int frow = nodebase + ln;
  int frowc = (frow < NN) ? frow : (NN - 1);
  short8 zp[3][4];  // post-GEMM z' A-fragments, all 3 m
#pragma unroll
  for (int m = 0; m < 3; ++m) {
    // A-frags of pre-GEMM z
    const short8* zr = (const short8*)(Z + ((size_t)m * NN + frowc) * 128);
    short8 a0 = zr[quad], a1 = zr[4 + quad], a2 = zr[8 + quad], a3 = zr[12 + quad];
    // GEMM: z @ W_m (B from prepped [n][k] bf16)
    const unsigned short* wb = wbf + (size_t)m * DD * DD;
    floatx4 acc[8];
#pragma unroll
    for (int c = 0; c < 8; ++c) acc[c] = (floatx4){0.f, 0.f, 0.f, 0.f};
#pragma unroll
    for (int kt = 0; kt < 4; ++kt) {
      short8 a = (kt == 0) ? a0 : (kt == 1) ? a1 : (kt == 2) ? a2 : a3;
#pragma unroll
      for (int c = 0; c < 8; ++c) {
        short8 b = *(const short8*)(wb + (size_t)(c * 16 + ln) * DD + kt * 32 + quad * 8);
        acc[c] = __builtin_amdgcn_mfma_f32_16x16x32_bf16(a, b, acc[c], 0, 0, 0);
      }
    }
    // bias + pack to per-wave LDS slab in C layout (row=quad*4+r, col=c*16+ln)
    const float* bias = Ball + (size_t)m * DD;
#pragma unroll
    for (int c = 0; c < 8; ++c) {
      int col = c * 16 + ln;
      float bs = bias[col];
#pragma unroll
      for (int r = 0; r < 4; ++r) zt[wave][quad * 4 + r][col] = f2bf(acc[c][r] + bs);
    }
    __syncthreads();
    // re-read in A-fragment layout
#pragma unroll
    for (int kt = 0; kt < 4; ++kt)
      zp[m][kt] = *(const short8*)&zt[wave][ln][kt * 32 + quad * 8];
    __syncthreads();
  }
  // attention scores per m from in-register z'
#pragma unroll
  for (int m = 0; m < 3; ++m) {
    floatx4 acc[8];
#pragma unroll
    for (int c = 0; c < 8; ++c) acc[c] = (floatx4){0.f, 0.f, 0.f, 0.f};
#pragma unroll
    for (int kt = 0; kt < 4; ++kt) {
#pragma unroll
      for (int c = 0; c < 8; ++c) {
        short8 b = *(const short8*)(wb1 + (size_t)(c * 16 + ln) * DD + kt * 32 + quad * 8);
        acc[c] = __builtin_amdgcn_mfma_f32_16x16x32_bf16(zp[m][kt], b, acc[c], 0, 0, 0);
      }
    }
    float rows[4] = {0.f, 0.f, 0.f, 0.f};
#pragma unroll
    for (int c = 0; c < 8; ++c) {
      int col = c * 16 + ln;
      float bb = b1[col];
      float ww = w2[col];
#pragma unroll
      for (int r = 0; r < 4; ++r) rows[r] += tanh_apx(acc[c][r] + bb) * ww;
    }
#pragma unroll
    for (int off = 8; off > 0; off >>= 1) {
#pragma unroll
      for (int r = 0; r < 4; ++r) rows[r] += __shfl_down(rows[r], off);
    }
    if (ln == 0) {
#pragma unroll
      for (int r = 0; r < 4; ++r) sc[wave][m][quad * 4 + r] = rows[r];
    }
  }
  __syncthreads();
  float s0 = sc[wave][0][ln], s1 = sc[wave][1][ln], s2 = sc[wave][2][ln];
  float mx = fmaxf(s0, fmaxf(s1, s2));
  float e0 = __expf(s0 - mx), e1 = __expf(s1 - mx), e2 = __expf(s2 - mx);
  float inv = 1.0f / (e0 + e1 + e2);
  float bb0 = e0 * inv, bb1 = e1 * inv, bb2 = e2 * inv;
  float o[4][8];
#pragma unroll
  for (int kt = 0; kt < 4; ++kt) {
#pragma unroll
    for (int j = 0; j < 8; ++j) {
      o[kt][j] = bb0 * bf2f(zp[0][kt][j]) + bb1 * bf2f(zp[1][kt][j]) + bb2 * bf2f(zp[2][kt][j]);
    }
  }
  if (!last) {
    if (frow < NN) {
#pragma unroll
      for (int kt = 0; kt < 4; ++kt) {
        uint2 v;
        v.x = pack_fp8x4(o[kt][0] * HSCALE, o[kt][1] * HSCALE, o[kt][2] * HSCALE,
                         o[kt][3] * HSCALE);
        v.y = pack_fp8x4(o[kt][4] * HSCALE, o[kt][5] * HSCALE, o[kt][6] * HSCALE,
                         o[kt][7] * HSCALE);
        *(uint2*)&hq[(size_t)frow * 32 + kt * 8 + quad * 2] = v;
      }
    }
  } else {
    float vmx = o[0][0];
#pragma unroll
    for (int kt = 0; kt < 4; ++kt)
#pragma unroll
      for (int j = 0; j < 8; ++j) vmx = fmaxf(vmx, o[kt][j]);
    vmx = fmaxf(vmx, __shfl_xor(vmx, 16));
    vmx = fmaxf(vmx, __shfl_xor(vmx, 32));
    float ss = 0.f;
#pragma unroll
    for (int kt = 0; kt < 4; ++kt)
#pragma unroll
      for (int j = 0; j < 8; ++j) ss += __expf(o[kt][j] - vmx);
    ss += __shfl_xor(ss, 16);
    ss += __shfl_xor(ss, 32);
    float lse = vmx + logf(ss);
    if (frow < NN) {
#pragma unroll
      for (int kt = 0; kt < 4; ++kt) {
        float4 a, b;
        a.x = o[kt][0] - lse; a.y = o[kt][1] - lse; a.z = o[kt][2] - lse; a.w = o[kt][3] - lse;
        b.x = o[kt][4] - lse; b.y = o[kt][5] - lse; b.z = o[kt][6] - lse; b.w = o[kt][7] - lse;
        float* dst = fout + (size_t)frow * 128 + kt * 32 + quad * 8;
        *(float4*)dst = a;
        *(float4*)(dst + 4) = b;
      }
    }
  }
}

extern "C" void kernel_launch(void* const* d_in, const int* in_sizes, int n_in,
                              void* d_out, int out_size, void* d_ws, size_t ws_size,
                              hipStream_t stream) {
  const int* x = (const int*)d_in[0];
  const int* e0 = (const int*)d_in[1];
  const int* e1 = (const int*)d_in[2];
  const int* e2 = (const int*)d_in[3];
  const float* embed = (const float*)d_in[4];
  const float* W = (const float*)d_in[5];    // [2][3][128][128]
  const float* B = (const float*)d_in[6];    // [2][3][128]
  const float* aw1 = (const float*)d_in[7];  // [2][128][128]
  const float* ab1 = (const float*)d_in[8];  // [2][128]
  const float* aw2 = (const float*)d_in[9];  // [2][128]
  float* out = (float*)d_out;
  uint32_hip* hq = (uint32_hip*)d_out;  // fp8 h (12.8MB) lives in d_out until final layer

  char* ws = (char*)d_ws;
  size_t off = 0;
  auto alloc = [&](size_t bytes) {
    void* p = ws + off;
    off += (bytes + 255) & ~(size_t)255;
    return p;
  };
  unsigned short* z = (unsigned short*)alloc((size_t)MM * NN * DD * 2);  // 76.8 MB
  uint32_hip* lvl1 = (uint32_hip*)alloc((size_t)MM * ECHTOT * 4 + 4096); // 25.3 MB + overrun pad
  int* astart = (int*)alloc((size_t)MM * NN * 4);                        // 1.2 MB
  unsigned short* sdeg = (unsigned short*)alloc((size_t)MM * NN * 2);    // 0.6 MB
  int* ccount = (int*)alloc((size_t)MM * NC * 4);                        // ~2.4 KB
  int* cpad = (int*)alloc((size_t)MM * NC * 4);                          // ~2.4 KB
  uint2* pinfo = (uint2*)alloc((size_t)MM * NN * 8);                     // 2.4 MB
  int* thist = (int*)alloc((size_t)MM * NC * NTILES * 4);                // ~0.5 MB
  int* dthist = (int*)alloc((size_t)MM * DBINS * NT2P * 4);              // ~0.3 MB
  int* bintot = (int*)alloc((size_t)MM * DBINS * 4);                     // 6 KB
  int* binbase = (int*)alloc((size_t)MM * DBINS * 4);                    // 6 KB
  unsigned short* wbf = (unsigned short*)alloc((size_t)8 * DD * DD * 2); // 256 KB

  dim3 bs(256);
  wprep_kernel<<<dim3(512), bs, 0, stream>>>(W, aw1, wbf);
  hist1_kernel<<<dim3(NTILES, 3), bs, 0, stream>>>(e0, e1, e2, thist);
  scan1_kernel<<<dim3(NC, 3), bs, 0, stream>>>(thist, ccount);
  scatter1_kernel<<<dim3(NTILES, 3), bs, 0, stream>>>(e0, e1, e2, thist, ccount, lvl1);
  sort2_kernel<<<dim3(NC, 3), bs, 0, stream>>>(lvl1, ccount, astart, sdeg, cpad);
  norm_embed_kernel<<<dim3(NC, 3), bs, 0, stream>>>(lvl1, cpad, sdeg);
  dhist_kernel<<<dim3(NT2, 3), bs, 0, stream>>>(sdeg, dthist);
  dscan_kernel<<<dim3(DBINS, 3), dim3(64), 0, stream>>>(dthist, bintot);
  dscan2_kernel<<<dim3(3), dim3(DBINS), 0, stream>>>(bintot, binbase);
  dscatter_kernel<<<dim3(NT2, 3), bs, 0, stream>>>(sdeg, astart, dthist, binbase, pinfo);
  embed_kernel<<<dim3((NN * 32 + 255) / 256), bs, 0, stream>>>(x, embed, hq);

  for (int l = 0; l < 2; ++l) {
    agg_kernel<<<dim3(NN / 32, 3), bs, 0, stream>>>(
        (const uint32_hip*)hq, pinfo, lvl1, (uint32_hip*)z);
    gemm_att_kernel<<<dim3((NN + 63) / 64), bs, 0, stream>>>(
        z, wbf + (size_t)l * 3 * DD * DD, B + (size_t)l * 3 * DD,
        wbf + (size_t)(6 + l) * DD * DD, ab1 + (size_t)l * DD, aw2 + (size_t)l * DD,
        hq, out, l == 1);
  }
}

// Round 10
// 591.251 us; speedup vs baseline: 1.3735x; 1.3735x over previous
//
#include <hip/hip_runtime.h>
#include <hip/hip_bf16.h>

#define NN 100000
#define DD 128
#define MM 3
#define EE 1600000
#define CH_NODES 512                          // nodes per coarse chunk
#define NC ((NN + CH_NODES - 1) / CH_NODES)   // 196 coarse chunks
#define ECAP 10752                            // per-chunk PADDED capacity (8192 mean + 8.5σ + 3/node pad)
#define ECHTOT ((size_t)NC * ECAP)            // per-m CSR capacity
#define TILE_E 8192
#define NTILES ((EE + TILE_E - 1) / TILE_E)   // 196
#define DTILE 2048
#define NT2 ((NN + DTILE - 1) / DTILE)        // 49 node tiles for degsort
#define NT2P 52                               // padded pitch
#define DBINS 512
#define HSCALE 64.0f
#define HINV (1.0f / 64.0f)
#define PADMARK 0xFFFFFFFFu

typedef unsigned int uint32_hip;
typedef short short8 __attribute__((ext_vector_type(8)));
typedef float floatx4 __attribute__((ext_vector_type(4)));
typedef float floatx2 __attribute__((ext_vector_type(2)));

// ---- bf16 helpers ----
__device__ __forceinline__ float bf2f(short s) {
  return __uint_as_float(((uint32_hip)(unsigned short)s) << 16);
}
__device__ __forceinline__ unsigned short f2bf(float f) {
  union { __hip_bfloat16 b; unsigned short u; } cv;
  cv.b = __float2bfloat16(f);
  return cv.u;
}
__device__ __forceinline__ uint32_hip packbf2(float x, float y) {
  return (uint32_hip)f2bf(x) | ((uint32_hip)f2bf(y) << 16);
}
__device__ __forceinline__ float tanh_apx(float x) {
  float e = __expf(2.0f * x);
  return 1.0f - 2.0f / (e + 1.0f);
}
// pack 4 floats -> 4 fp8 e4m3 (OCP on gfx950) in one uint
__device__ __forceinline__ uint32_hip pack_fp8x4(float a, float b, float c, float d) {
  uint32_hip w = 0;
  w = __builtin_amdgcn_cvt_pk_fp8_f32(a, b, w, false);  // bytes 0,1
  w = __builtin_amdgcn_cvt_pk_fp8_f32(c, d, w, true);   // bytes 2,3
  return w;
}
// fp16 (in low 16 bits) -> f32
__device__ __forceinline__ float h2f(uint32_hip u) {
  union { unsigned short us; _Float16 h; } cv;
  cv.us = (unsigned short)u;
  return (float)cv.h;
}
__device__ __forceinline__ unsigned short f2h(float f) {
  union { unsigned short us; _Float16 h; } cv;
  cv.h = (_Float16)f;
  return cv.us;
}
// decode 16 fp8 (uint4) -> 8 float2
__device__ __forceinline__ void dec16(uint4 hv, floatx2* f) {
  f[0] = __builtin_amdgcn_cvt_pk_f32_fp8((int)hv.x, false);
  f[1] = __builtin_amdgcn_cvt_pk_f32_fp8((int)hv.x, true);
  f[2] = __builtin_amdgcn_cvt_pk_f32_fp8((int)hv.y, false);
  f[3] = __builtin_amdgcn_cvt_pk_f32_fp8((int)hv.y, true);
  f[4] = __builtin_amdgcn_cvt_pk_f32_fp8((int)hv.z, false);
  f[5] = __builtin_amdgcn_cvt_pk_f32_fp8((int)hv.z, true);
  f[6] = __builtin_amdgcn_cvt_pk_f32_fp8((int)hv.w, false);
  f[7] = __builtin_amdgcn_cvt_pk_f32_fp8((int)hv.w, true);
}

// ---------- prep: transpose+convert weights to bf16 [mat][n][k] ----------
// mats 0..5 = W[l][m]; mats 6..7 = att_w1[l]. Source is [k][n] f32.
__global__ __launch_bounds__(256) void wprep_kernel(const float* __restrict__ W,
                                                    const float* __restrict__ aw1,
                                                    unsigned short* __restrict__ wbf) {
  int tot = blockIdx.x * 256 + threadIdx.x;  // 8 * 16384
  int mat = tot >> 14;
  int i = tot & 16383;
  int n = i >> 7, k = i & 127;
  float v = (mat < 6) ? W[(size_t)mat * 16384 + k * 128 + n]
                      : aw1[(size_t)(mat - 6) * 16384 + k * 128 + n];
  wbf[tot] = f2bf(v);
}

// ---------- L1 pass A: per-tile coarse-chunk histogram -> thist[m][chunk][tile] ----------
__global__ __launch_bounds__(256) void hist1_kernel(const int* __restrict__ e0,
                                                    const int* __restrict__ e1,
                                                    const int* __restrict__ e2,
                                                    int* __restrict__ thist) {
  __shared__ int hist[NC];
  int m = blockIdx.y, tile = blockIdx.x, t = threadIdx.x;
  const int* ei = (m == 0) ? e0 : (m == 1) ? e1 : e2;
  const int* dst = ei + EE;
  int beg = tile * TILE_E, end = min(beg + TILE_E, EE);
  if (t < NC) hist[t] = 0;
  __syncthreads();
  for (int e = beg + t; e < end; e += 256) atomicAdd(&hist[dst[e] >> 9], 1);
  __syncthreads();
  int* th = thist + (size_t)m * NC * NTILES + tile;
  if (t < NC) th[(size_t)t * NTILES] = hist[t];
}

// ---------- L1 pass B: exclusive scan across tiles per (chunk,m) -> deterministic bases ----
__global__ __launch_bounds__(256) void scan1_kernel(int* __restrict__ thist,
                                                    int* __restrict__ ccount) {
  __shared__ int sw[256];
  int c = blockIdx.x, m = blockIdx.y, t = threadIdx.x;
  int* th = thist + ((size_t)m * NC + c) * NTILES;
  int v = (t < NTILES) ? th[t] : 0;
  sw[t] = v;
  __syncthreads();
  for (int off = 1; off < 256; off <<= 1) {
    int u = (t >= off) ? sw[t - off] : 0;
    __syncthreads();
    sw[t] += u;
    __syncthreads();
  }
  if (t < NTILES) th[t] = c * ECAP + sw[t] - v;  // exclusive base
  if (t == NTILES - 1) ccount[m * NC + c] = sw[t];
}

// ---------- L1 pass C: coarse scatter, LDS-sorted emit (runs of ~42 edges) ----------
__global__ __launch_bounds__(256) void scatter1_kernel(const int* __restrict__ e0,
                                                       const int* __restrict__ e1,
                                                       const int* __restrict__ e2,
                                                       const int* __restrict__ thist,
                                                       const int* __restrict__ ccount,
                                                       uint32_hip* __restrict__ lvl1) {
  __shared__ int gbase[NC];
  __shared__ int spos[NC];
  __shared__ int cur[NC];
  __shared__ int sw[256];
  __shared__ uint32_hip sval[TILE_E];
  __shared__ unsigned char sbuk[TILE_E];
  int m = blockIdx.y, tile = blockIdx.x, t = threadIdx.x;
  const int* ei = (m == 0) ? e0 : (m == 1) ? e1 : e2;
  const int* dst = ei + EE;
  const int* th = thist + (size_t)m * NC * NTILES + tile;
  int cnt = 0;
  if (t < NC) {
    int gb = th[(size_t)t * NTILES];
    int gn = (tile + 1 < NTILES) ? th[(size_t)t * NTILES + 1] : t * ECAP + ccount[m * NC + t];
    gbase[t] = gb;
    cnt = gn - gb;
  }
  sw[t] = cnt;
  __syncthreads();
  for (int off = 1; off < 256; off <<= 1) {
    int u = (t >= off) ? sw[t - off] : 0;
    __syncthreads();
    sw[t] += u;
    __syncthreads();
  }
  if (t < NC) {
    spos[t] = sw[t] - cnt;
    cur[t] = sw[t] - cnt;
  }
  __syncthreads();
  int beg = tile * TILE_E, end = min(beg + TILE_E, EE);
  int ct = end - beg;
  for (int e = beg + t; e < end; e += 256) {
    int s = ei[e], d = dst[e];
    int b = d >> 9;
    int r = atomicAdd(&cur[b], 1);
    sval[r] = (uint32_hip)s | ((uint32_hip)(d & 511) << 17);
    sbuk[r] = (unsigned char)b;
  }
  __syncthreads();
  uint32_hip* eb = lvl1 + (size_t)m * ECHTOT;
  for (int i = t; i < ct; i += 256) {
    int b = sbuk[i];
    eb[gbase[b] + (i - spos[b])] = sval[i];
  }
}

// ---------- L2: per-chunk 512-way counting sort in LDS, PADDED to 4/node ----------
__global__ __launch_bounds__(256) void sort2_kernel(uint32_hip* __restrict__ lvl1,
                                                    const int* __restrict__ ccount,
                                                    int* __restrict__ astart,
                                                    unsigned short* __restrict__ sdeg,
                                                    int* __restrict__ cpad) {
  __shared__ uint32_hip ebl[ECAP];
  __shared__ int cnt[CH_NODES];
  __shared__ int pos[CH_NODES];
  __shared__ int sw[256];
  int m = blockIdx.y, c = blockIdx.x, t = threadIdx.x;
  int base = c * ECAP;
  int ct = ccount[m * NC + c];
  uint32_hip* eb = lvl1 + (size_t)m * ECHTOT + base;
  for (int e = t; e < ct; e += 256) ebl[e] = eb[e];
  cnt[t] = 0;
  cnt[t + 256] = 0;
  __syncthreads();
  for (int e = t; e < ct; e += 256) atomicAdd(&cnt[ebl[e] >> 17], 1);
  __syncthreads();
  int c0 = cnt[2 * t], c1 = cnt[2 * t + 1];
  int p0 = (c0 + 3) & ~3, p1 = (c1 + 3) & ~3;  // padded run lengths
  int s = p0 + p1;
  sw[t] = s;
  __syncthreads();
  for (int off = 1; off < 256; off <<= 1) {
    int u = (t >= off) ? sw[t - off] : 0;
    __syncthreads();
    sw[t] += u;
    __syncthreads();
  }
  int excl = sw[t] - s;
  pos[2 * t] = excl;
  pos[2 * t + 1] = excl + p0;
  int node0 = c * CH_NODES;
  {
    int n0 = node0 + 2 * t;
    if (n0 < NN) {
      astart[(size_t)m * NN + n0] = base + excl;
      sdeg[(size_t)m * NN + n0] = (unsigned short)c0;
    }
    int n1 = node0 + 2 * t + 1;
    if (n1 < NN) {
      astart[(size_t)m * NN + n1] = base + excl + p0;
      sdeg[(size_t)m * NN + n1] = (unsigned short)c1;
    }
  }
  if (t == 255) cpad[m * NC + c] = sw[255];
  __syncthreads();
  for (int e = t; e < ct; e += 256) {
    uint32_hip p = ebl[e];
    int q = atomicAdd(&pos[p >> 17], 1);
    eb[q] = p & 0x1FFFFu;  // src only, node-sorted
  }
  // fill pad slots
  for (int i = c0; i < p0; ++i) eb[excl + i] = PADMARK;
  for (int i = c1; i < p1; ++i) eb[excl + p0 + i] = PADMARK;
}

// ---------- embed fp16 source-norm into upper 15 bits; pads become entry 0 ----------
__global__ void norm_embed_kernel(uint32_hip* __restrict__ lvl1, const int* __restrict__ cpad,
                                  const unsigned short* __restrict__ sdeg) {
  int m = blockIdx.y, c = blockIdx.x, t = threadIdx.x;
  int base = c * ECAP;
  int ct = cpad[m * NC + c];
  uint32_hip* eb = lvl1 + (size_t)m * ECHTOT + base;
  const unsigned short* sd = sdeg + (size_t)m * NN;
  for (int e = t; e < ct; e += 256) {
    uint32_hip p = eb[e];
    uint32_hip s = p & 0x1FFFFu;
    uint32_hip sc_ = (s < NN) ? s : 0;
    float dv = rsqrtf((float)(sd[sc_] + 1));
    eb[e] = (p == PADMARK) ? 0u : (s | ((uint32_hip)f2h(dv) << 17));
  }
}

// ---------- parallel degree sort: 4-stage tile radix -> pinfo[slot] ----------
__global__ __launch_bounds__(256) void dhist_kernel(const unsigned short* __restrict__ sdeg,
                                                    int* __restrict__ dthist) {
  __shared__ int hist[DBINS];
  int m = blockIdx.y, tile = blockIdx.x, t = threadIdx.x;
  const unsigned short* sd = sdeg + (size_t)m * NN;
  hist[t] = 0;
  hist[t + 256] = 0;
  __syncthreads();
  int beg = tile * DTILE, end = min(beg + DTILE, NN);
  for (int n = beg + t; n < end; n += 256) atomicAdd(&hist[min((int)sd[n], DBINS - 1)], 1);
  __syncthreads();
  int* th = dthist + ((size_t)m * DBINS) * NT2P + tile;
  th[(size_t)t * NT2P] = hist[t];
  th[(size_t)(t + 256) * NT2P] = hist[t + 256];
}

__global__ __launch_bounds__(64) void dscan_kernel(int* __restrict__ dthist,
                                                   int* __restrict__ bintot) {
  __shared__ int sw[64];
  int bin = blockIdx.x, m = blockIdx.y, t = threadIdx.x;
  int* th = dthist + ((size_t)m * DBINS + bin) * NT2P;
  int v = (t < NT2) ? th[t] : 0;
  sw[t] = v;
  __syncthreads();
  for (int off = 1; off < 64; off <<= 1) {
    int u = (t >= off) ? sw[t - off] : 0;
    __syncthreads();
    sw[t] += u;
    __syncthreads();
  }
  if (t < NT2) th[t] = sw[t] - v;  // exclusive within bin
  if (t == 63) bintot[m * DBINS + bin] = sw[63];
}

__global__ __launch_bounds__(512) void dscan2_kernel(const int* __restrict__ bintot,
                                                     int* __restrict__ binbase) {
  __shared__ int sw[DBINS];
  int m = blockIdx.x, t = threadIdx.x;
  int v = bintot[m * DBINS + t];
  sw[t] = v;
  __syncthreads();
  for (int off = 1; off < DBINS; off <<= 1) {
    int u = (t >= off) ? sw[t - off] : 0;
    __syncthreads();
    sw[t] += u;
    __syncthreads();
  }
  binbase[m * DBINS + t] = sw[t] - v;
}

__global__ __launch_bounds__(256) void dscatter_kernel(const unsigned short* __restrict__ sdeg,
                                                       const int* __restrict__ astart,
                                                       const int* __restrict__ dthist,
                                                       const int* __restrict__ binbase,
                                                       uint2* __restrict__ pinfo) {
  __shared__ int cur[DBINS];
  int m = blockIdx.y, tile = blockIdx.x, t = threadIdx.x;
  const unsigned short* sd = sdeg + (size_t)m * NN;
  const int* as_ = astart + (size_t)m * NN;
  for (int b = t; b < DBINS; b += 256)
    cur[b] = binbase[m * DBINS + b] + dthist[((size_t)m * DBINS + b) * NT2P + tile];
  __syncthreads();
  uint2* pi = pinfo + (size_t)m * NN;
  int beg = tile * DTILE, end = min(beg + DTILE, NN);
  for (int n = beg + t; n < end; n += 256) {
    int d = sd[n];
    int r = atomicAdd(&cur[min(d, DBINS - 1)], 1);
    int slot = NN - 1 - r;  // descending degree -> heavy blocks launch first
    uint2 v;
    v.x = (uint32_hip)as_[n];
    v.y = (uint32_hip)n | ((uint32_hip)d << 17);
    pi[slot] = v;
  }
}

// ---------- embedding gather -> fp8 h (x64 scale), lives in d_out ----------
__global__ void embed_kernel(const int* __restrict__ x, const float* __restrict__ tbl,
                             uint32_hip* __restrict__ hq) {
  int i = blockIdx.x * 256 + threadIdx.x;
  if (i < NN * 32) {
    int n = i >> 5;
    int c = i & 31;
    float4 v = ((const float4*)tbl)[(size_t)x[n] * 32 + c];
    hq[(size_t)n * 32 + c] =
        pack_fp8x4(v.x * HSCALE, v.y * HSCALE, v.z * HSCALE, v.w * HSCALE);
  }
}

// ---------- normalized aggregation (fp8 h -> bf16 z), STANDALONE ----------
// 8 nodes/wave (degree-sorted, descending), 8 lanes/node, dwordx4 gathers,
// 4 edges/iter; CSR quad for iter i+1 prefetched during iter i.
__global__ __launch_bounds__(256) void agg_kernel(const uint32_hip* __restrict__ hq,
                                                  const uint2* __restrict__ pinfo,
                                                  const uint32_hip* __restrict__ csr,
                                                  uint32_hip* __restrict__ zall) {
  int m = blockIdx.y;
  const uint2* pi_ = pinfo + (size_t)m * NN;
  const uint32_hip* cs = csr + (size_t)m * ECHTOT;
  uint32_hip* zo = zall + (size_t)m * NN * 64;
  int t = threadIdx.x;
  int wave = t >> 6, lane = t & 63;
  int g = lane >> 3, l = lane & 7;              // group (node) / lane within group
  int slot = blockIdx.x * 32 + wave * 8 + g;    // 100000 = 32 * 3125 -> exact grid
  uint2 pi = pi_[slot];
  int e = (int)pi.x;
  int n = (int)(pi.y & 0x1FFFFu);
  int deg = (int)(pi.y >> 17);
  float di = rsqrtf((float)(deg + 1));
  floatx2 ac[8];
  {
    uint4 hv = *(const uint4*)(hq + (size_t)n * 32 + l * 4);
    floatx2 f[8];
    dec16(hv, f);
    floatx2 di2 = {di, di};
#pragma unroll
    for (int j = 0; j < 8; ++j) ac[j] = di2 * f[j];
  }
  int end = e + ((deg + 3) & ~3);
  uint4 ce = *(const uint4*)(cs + e);  // first quad (bounded; pad covers overrun)
  while (__any(e < end)) {
    int en = e + 4;
    uint4 cn = *(const uint4*)(cs + en);  // prefetch next quad
    uint32_hip msk = (e < end) ? 0xFFFFFFFFu : 0u;
    uint32_hip cearr[4] = {ce.x & msk, ce.y & msk, ce.z & msk, ce.w & msk};
#pragma unroll
    for (int k = 0; k < 4; ++k) {
      uint32_hip ck = cearr[k];
      float nk = h2f(ck >> 17);
      int sk = ck & 0x1FFFF;
      uint4 hk = *(const uint4*)(hq + (size_t)sk * 32 + l * 4);
      floatx2 fk[8];
      dec16(hk, fk);
      floatx2 n2 = {nk, nk};
#pragma unroll
      for (int j = 0; j < 8; ++j) ac[j] = __builtin_elementwise_fma(n2, fk[j], ac[j]);
    }
    ce = cn;
    e = en;
  }
  float scv = di * HINV;
  floatx2 sc2 = {scv, scv};
#pragma unroll
  for (int j = 0; j < 8; ++j) ac[j] = ac[j] * sc2;
  uint4 w0, w1;
  w0.x = packbf2(ac[0].x, ac[0].y);
  w0.y = packbf2(ac[1].x, ac[1].y);
  w0.z = packbf2(ac[2].x, ac[2].y);
  w0.w = packbf2(ac[3].x, ac[3].y);
  w1.x = packbf2(ac[4].x, ac[4].y);
  w1.y = packbf2(ac[5].x, ac[5].y);
  w1.z = packbf2(ac[6].x, ac[6].y);
  w1.w = packbf2(ac[7].x, ac[7].y);
  uint32_hip* zr = zo + (size_t)n * 64 + l * 8;
  *(uint4*)zr = w0;
  *(uint4*)(zr + 4) = w1;
}

// ---------- FUSED GEMM + semantic attention + combine (+ final log_softmax) ----------
// Weights staged to LDS as bf16 (uint4 copy of prepped wbf, L2-hot), one 34KB
// buffer reused across {W0,W1,W2,attW1}. B-frags via ds_read_b128. C->A layout
// transpose via per-wave LDS slab. Deletes the standalone GEMM kernel and its
// 150MB/layer z round-trip.
__global__ __launch_bounds__(256) void gemm_att_kernel(
    const unsigned short* __restrict__ Z, const unsigned short* __restrict__ wbf,
    const float* __restrict__ Ball, const unsigned short* __restrict__ wb1,
    const float* __restrict__ b1, const float* __restrict__ w2,
    uint32_hip* __restrict__ hq, float* __restrict__ fout, int last) {
  __shared__ unsigned short wst[128][136];  // staged weight matrix (bf16)
  __shared__ unsigned short zt[4][16][136]; // per-wave C->A transpose slab
  __shared__ float sc[4][3][16];
  int t = threadIdx.x;
  int wave = t >> 6, lane = t & 63;
  int quad = lane >> 4, ln = lane & 15;
  int nodebase = blockIdx.x * 64 + wave * 16;
  int frow = nodebase + ln;
  int frowc = (frow < NN) ? frow : (NN - 1);
  short8 zp[3][4];  // post-GEMM z' A-fragments, all 3 m
#pragma unroll
  for (int m = 0; m < 3; ++m) {
    // stage W_m (bf16 [n][k], 32KB) into LDS
    {
      const uint4* src = (const uint4*)(wbf + (size_t)m * DD * DD);
      for (int i = t; i < 2048; i += 256) {
        int row = i >> 4, c8 = i & 15;
        *(uint4*)&wst[row][c8 * 8] = src[i];
      }
    }
    __syncthreads();
    // A-frags of pre-GEMM z
    const short8* zr = (const short8*)(Z + ((size_t)m * NN + frowc) * 128);
    short8 a0 = zr[quad], a1 = zr[4 + quad], a2 = zr[8 + quad], a3 = zr[12 + quad];
    floatx4 acc[8];
#pragma unroll
    for (int c = 0; c < 8; ++c) acc[c] = (floatx4){0.f, 0.f, 0.f, 0.f};
#pragma unroll
    for (int kt = 0; kt < 4; ++kt) {
      short8 a = (kt == 0) ? a0 : (kt == 1) ? a1 : (kt == 2) ? a2 : a3;
#pragma unroll
      for (int c = 0; c < 8; ++c) {
        short8 b = *(const short8*)&wst[c * 16 + ln][kt * 32 + quad * 8];
        acc[c] = __builtin_amdgcn_mfma_f32_16x16x32_bf16(a, b, acc[c], 0, 0, 0);
      }
    }
    // bias + pack to per-wave LDS slab in C layout (row=quad*4+r, col=c*16+ln)
    const float* bias = Ball + (size_t)m * DD;
#pragma unroll
    for (int c = 0; c < 8; ++c) {
      int col = c * 16 + ln;
      float bs = bias[col];
#pragma unroll
      for (int r = 0; r < 4; ++r) zt[wave][quad * 4 + r][col] = f2bf(acc[c][r] + bs);
    }
    // re-read in A-fragment layout (wave-internal LDS dependency; then block
    // barrier before next stage overwrites wst)
#pragma unroll
    for (int kt = 0; kt < 4; ++kt)
      zp[m][kt] = *(const short8*)&zt[wave][ln][kt * 32 + quad * 8];
    __syncthreads();
  }
  // stage att W1 into LDS
  {
    const uint4* src = (const uint4*)wb1;
    for (int i = t; i < 2048; i += 256) {
      int row = i >> 4, c8 = i & 15;
      *(uint4*)&wst[row][c8 * 8] = src[i];
    }
  }
  __syncthreads();
  // attention scores per m from in-register z'
#pragma unroll
  for (int m = 0; m < 3; ++m) {
    floatx4 acc[8];
#pragma unroll
    for (int c = 0; c < 8; ++c) acc[c] = (floatx4){0.f, 0.f, 0.f, 0.f};
#pragma unroll
    for (int kt = 0; kt < 4; ++kt) {
#pragma unroll
      for (int c = 0; c < 8; ++c) {
        short8 b = *(const short8*)&wst[c * 16 + ln][kt * 32 + quad * 8];
        acc[c] = __builtin_amdgcn_mfma_f32_16x16x32_bf16(zp[m][kt], b, acc[c], 0, 0, 0);
      }
    }
    float rows[4] = {0.f, 0.f, 0.f, 0.f};
#pragma unroll
    for (int c = 0; c < 8; ++c) {
      int col = c * 16 + ln;
      float bb = b1[col];
      float ww = w2[col];
#pragma unroll
      for (int r = 0; r < 4; ++r) rows[r] += tanh_apx(acc[c][r] + bb) * ww;
    }
#pragma unroll
    for (int off = 8; off > 0; off >>= 1) {
#pragma unroll
      for (int r = 0; r < 4; ++r) rows[r] += __shfl_down(rows[r], off);
    }
    if (ln == 0) {
#pragma unroll
      for (int r = 0; r < 4; ++r) sc[wave][m][quad * 4 + r] = rows[r];
    }
  }
  __syncthreads();
  float s0 = sc[wave][0][ln], s1 = sc[wave][1][ln], s2 = sc[wave][2][ln];
  float mx = fmaxf(s0, fmaxf(s1, s2));
  float e0 = __expf(s0 - mx), e1 = __expf(s1 - mx), e2 = __expf(s2 - mx);
  float inv = 1.0f / (e0 + e1 + e2);
  float bb0 = e0 * inv, bb1 = e1 * inv, bb2 = e2 * inv;
  float o[4][8];
#pragma unroll
  for (int kt = 0; kt < 4; ++kt) {
#pragma unroll
    for (int j = 0; j < 8; ++j) {
      o[kt][j] = bb0 * bf2f(zp[0][kt][j]) + bb1 * bf2f(zp[1][kt][j]) + bb2 * bf2f(zp[2][kt][j]);
    }
  }
  if (!last) {
    if (frow < NN) {
#pragma unroll
      for (int kt = 0; kt < 4; ++kt) {
        uint2 v;
        v.x = pack_fp8x4(o[kt][0] * HSCALE, o[kt][1] * HSCALE, o[kt][2] * HSCALE,
                         o[kt][3] * HSCALE);
        v.y = pack_fp8x4(o[kt][4] * HSCALE, o[kt][5] * HSCALE, o[kt][6] * HSCALE,
                         o[kt][7] * HSCALE);
        *(uint2*)&hq[(size_t)frow * 32 + kt * 8 + quad * 2] = v;
      }
    }
  } else {
    float vmx = o[0][0];
#pragma unroll
    for (int kt = 0; kt < 4; ++kt)
#pragma unroll
      for (int j = 0; j < 8; ++j) vmx = fmaxf(vmx, o[kt][j]);
    vmx = fmaxf(vmx, __shfl_xor(vmx, 16));
    vmx = fmaxf(vmx, __shfl_xor(vmx, 32));
    float ss = 0.f;
#pragma unroll
    for (int kt = 0; kt < 4; ++kt)
#pragma unroll
      for (int j = 0; j < 8; ++j) ss += __expf(o[kt][j] - vmx);
    ss += __shfl_xor(ss, 16);
    ss += __shfl_xor(ss, 32);
    float lse = vmx + logf(ss);
    if (frow < NN) {
#pragma unroll
      for (int kt = 0; kt < 4; ++kt) {
        float4 a, b;
        a.x = o[kt][0] - lse; a.y = o[kt][1] - lse; a.z = o[kt][2] - lse; a.w = o[kt][3] - lse;
        b.x = o[kt][4] - lse; b.y = o[kt][5] - lse; b.z = o[kt][6] - lse; b.w = o[kt][7] - lse;
        float* dst = fout + (size_t)frow * 128 + kt * 32 + quad * 8;
        *(float4*)dst = a;
        *(float4*)(dst + 4) = b;
      }
    }
  }
}

extern "C" void kernel_launch(void* const* d_in, const int* in_sizes, int n_in,
                              void* d_out, int out_size, void* d_ws, size_t ws_size,
                              hipStream_t stream) {
  const int* x = (const int*)d_in[0];
  const int* e0 = (const int*)d_in[1];
  const int* e1 = (const int*)d_in[2];
  const int* e2 = (const int*)d_in[3];
  const float* embed = (const float*)d_in[4];
  const float* W = (const float*)d_in[5];    // [2][3][128][128]
  const float* B = (const float*)d_in[6];    // [2][3][128]
  const float* aw1 = (const float*)d_in[7];  // [2][128][128]
  const float* ab1 = (const float*)d_in[8];  // [2][128]
  const float* aw2 = (const float*)d_in[9];  // [2][128]
  float* out = (float*)d_out;
  uint32_hip* hq = (uint32_hip*)d_out;  // fp8 h (12.8MB) lives in d_out until final layer

  char* ws = (char*)d_ws;
  size_t off = 0;
  auto alloc = [&](size_t bytes) {
    void* p = ws + off;
    off += (bytes + 255) & ~(size_t)255;
    return p;
  };
  unsigned short* z = (unsigned short*)alloc((size_t)MM * NN * DD * 2);  // 76.8 MB
  uint32_hip* lvl1 = (uint32_hip*)alloc((size_t)MM * ECHTOT * 4 + 4096); // 25.3 MB + overrun pad
  int* astart = (int*)alloc((size_t)MM * NN * 4);                        // 1.2 MB
  unsigned short* sdeg = (unsigned short*)alloc((size_t)MM * NN * 2);    // 0.6 MB
  int* ccount = (int*)alloc((size_t)MM * NC * 4);                        // ~2.4 KB
  int* cpad = (int*)alloc((size_t)MM * NC * 4);                          // ~2.4 KB
  uint2* pinfo = (uint2*)alloc((size_t)MM * NN * 8);                     // 2.4 MB
  int* thist = (int*)alloc((size_t)MM * NC * NTILES * 4);                // ~0.5 MB
  int* dthist = (int*)alloc((size_t)MM * DBINS * NT2P * 4);              // ~0.3 MB
  int* bintot = (int*)alloc((size_t)MM * DBINS * 4);                     // 6 KB
  int* binbase = (int*)alloc((size_t)MM * DBINS * 4);                    // 6 KB
  unsigned short* wbf = (unsigned short*)alloc((size_t)8 * DD * DD * 2); // 256 KB

  dim3 bs(256);
  wprep_kernel<<<dim3(512), bs, 0, stream>>>(W, aw1, wbf);
  hist1_kernel<<<dim3(NTILES, 3), bs, 0, stream>>>(e0, e1, e2, thist);
  scan1_kernel<<<dim3(NC, 3), bs, 0, stream>>>(thist, ccount);
  scatter1_kernel<<<dim3(NTILES, 3), bs, 0, stream>>>(e0, e1, e2, thist, ccount, lvl1);
  sort2_kernel<<<dim3(NC, 3), bs, 0, stream>>>(lvl1, ccount, astart, sdeg, cpad);
  norm_embed_kernel<<<dim3(NC, 3), bs, 0, stream>>>(lvl1, cpad, sdeg);
  dhist_kernel<<<dim3(NT2, 3), bs, 0, stream>>>(sdeg, dthist);
  dscan_kernel<<<dim3(DBINS, 3), dim3(64), 0, stream>>>(dthist, bintot);
  dscan2_kernel<<<dim3(3), dim3(DBINS), 0, stream>>>(bintot, binbase);
  dscatter_kernel<<<dim3(NT2, 3), bs, 0, stream>>>(sdeg, astart, dthist, binbase, pinfo);
  embed_kernel<<<dim3((NN * 32 + 255) / 256), bs, 0, stream>>>(x, embed, hq);

  for (int l = 0; l < 2; ++l) {
    agg_kernel<<<dim3(NN / 32, 3), bs, 0, stream>>>(
        (const uint32_hip*)hq, pinfo, lvl1, (uint32_hip*)z);
    gemm_att_kernel<<<dim3((NN + 63) / 64), bs, 0, stream>>>(
        z, wbf + (size_t)l * 3 * DD * DD, B + (size_t)l * 3 * DD,
        wbf + (size_t)(6 + l) * DD * DD, ab1 + (size_t)l * DD, aw2 + (size_t)l * DD,
        hq, out, l == 1);
  }
}